// Round 6
// baseline (288.060 us; speedup 1.0000x reference)
//
#include <hip/hip_runtime.h>
#include <hip/hip_bf16.h>

typedef __bf16 bf16x8 __attribute__((ext_vector_type(8)));
typedef float f32x4 __attribute__((ext_vector_type(4)));
typedef int v8i __attribute__((ext_vector_type(8)));

#define NB 8
#define ND 512
#define NT 2048
#define NCODES 4096
#define NM (NB * NT)
#define MARGIN_F 0.2f
#define ENC_STRIDE 320

// MX fragment image (Zq, Cq), fp8 e4m3:
//   tile (R_, K_) = 128 rows x 128 k = 16 KB at ((R_*4 + K_) * 16384)
//   fragment rg (0..7) = 16 rows x 128 k = 2048 B at rg*2048 within tile
//   bytes [0,1024): lane l's 16 B at l*16 = row rg*16+(l&15), k = (l>>4)*32 + 0..15
//   bytes [1024,2048): same lanes, k = (l>>4)*32 + 16..31
// A strip (fixed M_, all K_) = 64 KB contiguous -> staged whole into LDS once.

static __device__ inline unsigned short f2bf(float v) {
    __hip_bfloat16 h = __float2bfloat16(v);
    return __builtin_bit_cast(unsigned short, h);
}

static __device__ inline void async_copy16(const void* g, void* l) {
    __builtin_amdgcn_global_load_lds(
        (const __attribute__((address_space(1))) unsigned int*)g,
        (__attribute__((address_space(3))) unsigned int*)l, 16, 0, 0);
}

// ---- kernel 1: student (B,D,T) fp32 -> fp8 fragment image Zq + bf16 row-major Zrm ----
__global__ void student_prep(const float* __restrict__ sf, unsigned char* __restrict__ Zq,
                             unsigned short* __restrict__ Zrm) {
    __shared__ float tile[128][65];  // [d_local][t_local]
    const int b = blockIdx.z;
    const int t0 = blockIdx.x * 64;
    const int d0 = blockIdx.y * 128;
    const int tid = threadIdx.x;  // 256
    const float* src = sf + (size_t)b * ND * NT;
#pragma unroll
    for (int it = 0; it < 8; it++) {
        int idx = it * 256 + tid;
        int d = idx >> 4, t4 = (idx & 15) * 4;
        float4 v = *(const float4*)(src + (size_t)(d0 + d) * NT + t0 + t4);  // coalesced
        tile[d][t4] = v.x; tile[d][t4 + 1] = v.y; tile[d][t4 + 2] = v.z; tile[d][t4 + 3] = v.w;
    }
    __syncthreads();
    const int wave = tid >> 6, lane = tid & 63, l15 = lane & 15, kq = lane >> 4;
    const int m0 = b * NT + t0;
    // fp8 fragment emit: wave w -> fragment rg0+w; lane: row w*16+l15, k kq*32+j
    {
        const int trow = wave * 16 + l15;
        unsigned char q[32];
#pragma unroll
        for (int j = 0; j < 32; j += 2) {
            float a = tile[kq * 32 + j][trow];
            float c = tile[kq * 32 + j + 1][trow];
            int p = __builtin_amdgcn_cvt_pk_fp8_f32(a, c, 0, false);
            q[j] = (unsigned char)(p & 0xFF);
            q[j + 1] = (unsigned char)((p >> 8) & 0xFF);
        }
        const int M_ = m0 >> 7, rg = ((m0 >> 4) & 7) + wave, K_ = d0 >> 7;
        char* base = (char*)Zq + ((size_t)((M_ * 4 + K_) * 8 + rg)) * 2048;
        *(uint4*)(base + lane * 16) = *(uint4*)&q[0];
        *(uint4*)(base + 1024 + lane * 16) = *(uint4*)&q[16];
    }
    // bf16 row-major emit for the refine kernel
    {
        int t = tid >> 2;
#pragma unroll
        for (int it = 0; it < 8; it++) {
            int d = (tid & 3) * 4 + it * 16;
            ushort4 o;
            o.x = f2bf(tile[d][t]); o.y = f2bf(tile[d + 1][t]);
            o.z = f2bf(tile[d + 2][t]); o.w = f2bf(tile[d + 3][t]);
            *(ushort4*)(Zrm + (size_t)(m0 + t) * ND + d0 + d) = o;
        }
    }
}

// ---- kernel 2: codebook fp32 -> fp8 fragment image Cq + row norms + ticket zero ----
__global__ void codebook_prep(const float* __restrict__ cb, unsigned char* __restrict__ Cq,
                              float* __restrict__ cnorm, float* __restrict__ accum,
                              unsigned int* __restrict__ ticket) {
    const int tid = threadIdx.x;  // 256; grid 256 blocks (16 rows each, all K)
    if (blockIdx.x == 0 && tid == 0) { *accum = 0.0f; *ticket = 0u; }
    const int wave = tid >> 6, lane = tid & 63, l15 = lane & 15, kq = lane >> 4;
    const int r0 = blockIdx.x * 16;
    const int row = r0 + l15;
    const int K_ = wave;  // each wave handles one 128-k quarter
    const float* src = cb + (size_t)row * ND + K_ * 128 + kq * 32;
    unsigned char q[32];
    float s = 0.0f;
#pragma unroll
    for (int j4 = 0; j4 < 8; j4++) {
        float4 v = *(const float4*)(src + j4 * 4);
        s += v.x * v.x + v.y * v.y + v.z * v.z + v.w * v.w;
        int p0 = __builtin_amdgcn_cvt_pk_fp8_f32(v.x, v.y, 0, false);
        int p1 = __builtin_amdgcn_cvt_pk_fp8_f32(v.z, v.w, 0, false);
        q[j4 * 4 + 0] = (unsigned char)(p0 & 0xFF);
        q[j4 * 4 + 1] = (unsigned char)((p0 >> 8) & 0xFF);
        q[j4 * 4 + 2] = (unsigned char)(p1 & 0xFF);
        q[j4 * 4 + 3] = (unsigned char)((p1 >> 8) & 0xFF);
    }
    const int N_ = r0 >> 7, rg = (r0 >> 4) & 7;
    char* base = (char*)Cq + ((size_t)((N_ * 4 + K_) * 8 + rg)) * 2048;
    *(uint4*)(base + lane * 16) = *(uint4*)&q[0];
    *(uint4*)(base + 1024 + lane * 16) = *(uint4*)&q[16];
    // norms: fold kq subgroups (lane bits 4,5), then the 4 K_ waves via LDS
    s += __shfl_xor(s, 16);
    s += __shfl_xor(s, 32);
    __shared__ float red[4][16];
    if (lane < 16) red[wave][l15] = s;
    __syncthreads();
    if (tid < 16) cnorm[r0 + tid] = red[0][tid] + red[1][tid] + red[2][tid] + red[3][tid];
}

// ---- kernel 3: MX-fp8 GEMM, A-strip resident in LDS, B from L2 into registers ----
__global__ __launch_bounds__(256, 2) void triplet_main(
    const unsigned char* __restrict__ Zq, const unsigned char* __restrict__ Cq,
    const float* __restrict__ cnorm, const int* __restrict__ teacher,
    unsigned int* __restrict__ minq) {
    __shared__ __align__(16) unsigned char As[65536];  // full 128-row x 512-k strip

    const int M_ = blockIdx.x;   // x-major => XCD = M_ % 8 for all nq: strip stays L2-local
    const int nq = blockIdx.y;   // 0..7
    const int m0 = M_ * 128;
    const int tid = threadIdx.x;
    const int wave = tid >> 6, lane = tid & 63;
    const int wr = wave >> 1, wc = wave & 1;
    const int l15 = lane & 15, quad = lane >> 4;

    // stage the whole A strip once (64 chunks of 1 KB; 16 per wave), single barrier
    {
        const char* gA = (const char*)Zq + (size_t)M_ * 65536 + wave * 16384 + lane * 16;
        char* lA = (char*)As + wave * 16384;
#pragma unroll
        for (int i = 0; i < 16; i++) async_copy16(gA + i * 1024, lA + i * 1024);
    }

    unsigned int minu[4][4];
    int tch[4][4];
#pragma unroll
    for (int mi = 0; mi < 4; mi++)
#pragma unroll
        for (int r = 0; r < 4; r++) {
            minu[mi][r] = 0xFFFFFFFFu;
            tch[mi][r] = teacher[m0 + wr * 64 + mi * 16 + quad * 4 + r];
        }
    __syncthreads();  // A resident; no barriers after this point

    for (int nt = 0; nt < 4; nt++) {
        const int N_ = nq * 4 + nt;
        const int n0 = N_ * 128;
        const char* tB = (const char*)Cq + (size_t)N_ * 4 * 16384 + (wc * 4) * 2048 + lane * 16;
        f32x4 acc[4][4] = {};
        uint4 bq[4][2];
#pragma unroll
        for (int ni = 0; ni < 4; ni++) {
            bq[ni][0] = *(const uint4*)(tB + ni * 2048);
            bq[ni][1] = *(const uint4*)(tB + ni * 2048 + 1024);
        }
#pragma unroll
        for (int kt = 0; kt < 4; kt++) {
            uint4 bn[4][2];
            if (kt < 3) {
                const char* nB = tB + (kt + 1) * 16384;
#pragma unroll
                for (int ni = 0; ni < 4; ni++) {  // prefetch next kt's B (L2-resident)
                    bn[ni][0] = *(const uint4*)(nB + ni * 2048);
                    bn[ni][1] = *(const uint4*)(nB + ni * 2048 + 1024);
                }
            }
            v8i av[4];
#pragma unroll
            for (int mi = 0; mi < 4; mi++) {
                union { uint4 q[2]; v8i v; } u;
                const unsigned char* fb = As + ((kt * 8) + (wr * 4 + mi)) * 2048 + lane * 16;
                u.q[0] = *(const uint4*)fb;
                u.q[1] = *(const uint4*)(fb + 1024);
                av[mi] = u.v;
            }
#pragma unroll
            for (int mi = 0; mi < 4; mi++)
#pragma unroll
                for (int ni = 0; ni < 4; ni++) {
                    union { uint4 q[2]; v8i v; } u;
                    u.q[0] = bq[ni][0]; u.q[1] = bq[ni][1];
                    acc[mi][ni] = __builtin_amdgcn_mfma_scale_f32_16x16x128_f8f6f4(
                        av[mi], u.v, acc[mi][ni], 0, 0,
                        0, 0x7F7F7F7F, 0, 0x7F7F7F7F);  // scales = 1.0 (e8m0 127)
                }
            if (kt < 3) {
#pragma unroll
                for (int ni = 0; ni < 4; ni++) { bq[ni][0] = bn[ni][0]; bq[ni][1] = bn[ni][1]; }
            }
        }

        // fold: packed umin of (val-bits | col), teacher excluded
        float cn[4]; int col[4];
#pragma unroll
        for (int ni = 0; ni < 4; ni++) {
            col[ni] = n0 + wc * 64 + ni * 16 + l15;
            cn[ni] = cnorm[col[ni]];
        }
#pragma unroll
        for (int mi = 0; mi < 4; mi++)
#pragma unroll
            for (int r = 0; r < 4; r++) {
                int t = tch[mi][r];
#pragma unroll
                for (int ni = 0; ni < 4; ni++) {
                    float val = fmaxf(fmaf(-2.0f, acc[mi][ni][r], cn[ni]), 0.0f);
                    unsigned int u = (__builtin_bit_cast(unsigned int, val) & 0xFFFFF000u)
                                     | (unsigned int)col[ni];
                    u = (col[ni] == t) ? 0xFFFFFFFFu : u;
                    minu[mi][r] = min(minu[mi][r], u);
                }
            }
    }

    const int slot = nq * 2 + wc;  // 0..15
#pragma unroll
    for (int mi = 0; mi < 4; mi++)
#pragma unroll
        for (int r = 0; r < 4; r++) {
            unsigned int u = minu[mi][r];
#pragma unroll
            for (int off = 1; off < 16; off <<= 1) u = min(u, (unsigned int)__shfl_xor((int)u, off));
            if (l15 == 0) {
                int m = m0 + wr * 64 + mi * 16 + quad * 4 + r;
                minq[(size_t)slot * NM + m] = u;
            }
        }
}

// ---- kernel 4: refine (exact pos/neg) + masked triplet + ticketed finalize ----
__global__ void refine_final(const unsigned short* __restrict__ Zrm, const float* __restrict__ cb,
                             const unsigned int* __restrict__ minq, const int* __restrict__ teacher,
                             const int* __restrict__ lengths, float* __restrict__ accum,
                             unsigned int* __restrict__ ticket, float* __restrict__ out) {
    const int tid = threadIdx.x, wave = tid >> 6, lane = tid & 63;
    const int m = blockIdx.x * 4 + wave;
    // combine the 16 slot argmins
    unsigned int u = minq[(size_t)(lane & 15) * NM + m];
    u = min(u, (unsigned int)__shfl_xor((int)u, 1));
    u = min(u, (unsigned int)__shfl_xor((int)u, 2));
    u = min(u, (unsigned int)__shfl_xor((int)u, 4));
    u = min(u, (unsigned int)__shfl_xor((int)u, 8));
    const int ng = (int)(u & 0xFFFu);
    const int tch = teacher[m];
    // exact distances: bf16 z, fp32 codebook, fp32 accum
    bf16x8 z8 = *(const bf16x8*)(Zrm + (size_t)m * ND + lane * 8);
    const float* cn_ = cb + (size_t)ng * ND + lane * 8;
    const float* ct_ = cb + (size_t)tch * ND + lane * 8;
    float an = 0.0f, at = 0.0f;
#pragma unroll
    for (int i = 0; i < 2; i++) {
        float4 vn = *(const float4*)(cn_ + i * 4);
        float4 vt = *(const float4*)(ct_ + i * 4);
        float z0 = (float)z8[i * 4 + 0], z1 = (float)z8[i * 4 + 1];
        float z2 = (float)z8[i * 4 + 2], z3 = (float)z8[i * 4 + 3];
        float d;
        d = z0 - vn.x; an += d * d;  d = z0 - vt.x; at += d * d;
        d = z1 - vn.y; an += d * d;  d = z1 - vt.y; at += d * d;
        d = z2 - vn.z; an += d * d;  d = z2 - vt.z; at += d * d;
        d = z3 - vn.w; an += d * d;  d = z3 - vt.w; at += d * d;
    }
#pragma unroll
    for (int off = 1; off < 64; off <<= 1) {
        an += __shfl_xor(an, off);
        at += __shfl_xor(at, off);
    }
    __shared__ float red[4];
    if (lane == 0) {
        float negd = sqrtf(fmaxf(an, 1e-12f));
        float posd = sqrtf(fmaxf(at, 1e-12f));
        float tri = fmaxf(posd - negd + MARGIN_F, 0.0f);
        int t = m & (NT - 1);
        int b = m >> 11;
        int flen = lengths[b] / ENC_STRIDE;
        red[wave] = (t < flen) ? tri : 0.0f;
    }
    __syncthreads();
    if (tid == 0) {
        atomicAdd(accum, red[0] + red[1] + red[2] + red[3]);
        __threadfence();
        unsigned int old = atomicAdd(ticket, 1u);
        if (old == (unsigned int)(gridDim.x - 1)) {  // last block: all adds visible
            float total = atomicAdd(accum, 0.0f);
            float cnt = 0.0f;
            for (int b = 0; b < NB; b++) cnt += (float)(lengths[b] / ENC_STRIDE);
            out[0] = total / (cnt + 1e-8f);
        }
    }
}

extern "C" void kernel_launch(void* const* d_in, const int* in_sizes, int n_in,
                              void* d_out, int out_size, void* d_ws, size_t ws_size,
                              hipStream_t stream) {
    const float* sf = (const float*)d_in[0];
    const int* teacher = (const int*)d_in[1];
    const float* cb = (const float*)d_in[2];
    const int* lengths = (const int*)d_in[3];

    char* ws = (char*)d_ws;
    unsigned char* Zq = (unsigned char*)(ws);                  //  8,388,608 B
    unsigned char* Cq = (unsigned char*)(ws + 8388608);        //  2,097,152 B
    unsigned short* Zrm = (unsigned short*)(ws + 10485760);    // 16,777,216 B
    float* cnorm = (float*)(ws + 27262976);                    //     16,384 B
    unsigned int* minq = (unsigned int*)(ws + 27279360);       //  1,048,576 B
    float* accum = (float*)(ws + 28327936);                    //          4 B
    unsigned int* ticket = (unsigned int*)(ws + 28327940);     //          4 B

    student_prep<<<dim3(NT / 64, ND / 128, NB), 256, 0, stream>>>(sf, Zq, Zrm);
    codebook_prep<<<NCODES / 16, 256, 0, stream>>>(cb, Cq, cnorm, accum, ticket);
    triplet_main<<<dim3(128, 8), 256, 0, stream>>>(Zq, Cq, cnorm, teacher, minq);
    refine_final<<<NM / 4, 256, 0, stream>>>(Zrm, cb, minq, teacher, lengths, accum, ticket,
                                             (float*)d_out);
}

// Round 7
// 173.903 us; speedup vs baseline: 1.6564x; 1.6564x over previous
//
#include <hip/hip_runtime.h>
#include <hip/hip_bf16.h>

typedef __bf16 bf16x8 __attribute__((ext_vector_type(8)));
typedef float f32x4 __attribute__((ext_vector_type(4)));
typedef int v8i __attribute__((ext_vector_type(8)));

#define NB 8
#define ND 512
#define NT 2048
#define NCODES 4096
#define NM (NB * NT)
#define MARGIN_F 0.2f
#define ENC_STRIDE 320

// MX fragment image (Zq, Cq), fp8 e4m3:
//   tile (R_, K_) = 128 rows x 128 k = 16 KB at ((R_*4 + K_) * 16384)
//   fragment rg (0..7) = 16 rows x 128 k = 2048 B at rg*2048 within tile
//   bytes [0,1024): lane l's 16 B at l*16 = row rg*16+(l&15), k = (l>>4)*32 + 0..15
//   bytes [1024,2048): same lanes, k = (l>>4)*32 + 16..31
// A strip (fixed M_, all K_) = 64 KB contiguous -> staged whole into LDS once.

static __device__ inline unsigned short f2bf(float v) {
    __hip_bfloat16 h = __float2bfloat16(v);
    return __builtin_bit_cast(unsigned short, h);
}

static __device__ inline void async_copy16(const void* g, void* l) {
    __builtin_amdgcn_global_load_lds(
        (const __attribute__((address_space(1))) unsigned int*)g,
        (__attribute__((address_space(3))) unsigned int*)l, 16, 0, 0);
}

// ---- kernel 1: student (B,D,T) fp32 -> fp8 fragment image Zq + bf16 row-major Zrm ----
__global__ void student_prep(const float* __restrict__ sf, unsigned char* __restrict__ Zq,
                             unsigned short* __restrict__ Zrm) {
    __shared__ float tile[128][65];  // [d_local][t_local]
    const int b = blockIdx.z;
    const int t0 = blockIdx.x * 64;
    const int d0 = blockIdx.y * 128;
    const int tid = threadIdx.x;  // 256
    const float* src = sf + (size_t)b * ND * NT;
#pragma unroll
    for (int it = 0; it < 8; it++) {
        int idx = it * 256 + tid;
        int d = idx >> 4, t4 = (idx & 15) * 4;
        float4 v = *(const float4*)(src + (size_t)(d0 + d) * NT + t0 + t4);  // coalesced
        tile[d][t4] = v.x; tile[d][t4 + 1] = v.y; tile[d][t4 + 2] = v.z; tile[d][t4 + 3] = v.w;
    }
    __syncthreads();
    const int wave = tid >> 6, lane = tid & 63, l15 = lane & 15, kq = lane >> 4;
    const int m0 = b * NT + t0;
    // fp8 fragment emit: wave w -> fragment rg0+w; lane: row w*16+l15, k kq*32+j
    {
        const int trow = wave * 16 + l15;
        unsigned char q[32];
#pragma unroll
        for (int j = 0; j < 32; j += 2) {
            float a = tile[kq * 32 + j][trow];
            float c = tile[kq * 32 + j + 1][trow];
            int p = __builtin_amdgcn_cvt_pk_fp8_f32(a, c, 0, false);
            q[j] = (unsigned char)(p & 0xFF);
            q[j + 1] = (unsigned char)((p >> 8) & 0xFF);
        }
        const int M_ = m0 >> 7, rg = ((m0 >> 4) & 7) + wave, K_ = d0 >> 7;
        char* base = (char*)Zq + ((size_t)((M_ * 4 + K_) * 8 + rg)) * 2048;
        *(uint4*)(base + lane * 16) = *(uint4*)&q[0];
        *(uint4*)(base + 1024 + lane * 16) = *(uint4*)&q[16];
    }
    // bf16 row-major emit for the refine kernel
    {
        int t = tid >> 2;
#pragma unroll
        for (int it = 0; it < 8; it++) {
            int d = (tid & 3) * 4 + it * 16;
            ushort4 o;
            o.x = f2bf(tile[d][t]); o.y = f2bf(tile[d + 1][t]);
            o.z = f2bf(tile[d + 2][t]); o.w = f2bf(tile[d + 3][t]);
            *(ushort4*)(Zrm + (size_t)(m0 + t) * ND + d0 + d) = o;
        }
    }
}

// ---- kernel 2: codebook fp32 -> fp8 fragment image Cq + row norms ----
__global__ void codebook_prep(const float* __restrict__ cb, unsigned char* __restrict__ Cq,
                              float* __restrict__ cnorm) {
    const int tid = threadIdx.x;  // 256; grid 256 blocks (16 rows each, all K)
    const int wave = tid >> 6, lane = tid & 63, l15 = lane & 15, kq = lane >> 4;
    const int r0 = blockIdx.x * 16;
    const int row = r0 + l15;
    const int K_ = wave;  // each wave handles one 128-k quarter
    const float* src = cb + (size_t)row * ND + K_ * 128 + kq * 32;
    unsigned char q[32];
    float s = 0.0f;
#pragma unroll
    for (int j4 = 0; j4 < 8; j4++) {
        float4 v = *(const float4*)(src + j4 * 4);
        s += v.x * v.x + v.y * v.y + v.z * v.z + v.w * v.w;
        int p0 = __builtin_amdgcn_cvt_pk_fp8_f32(v.x, v.y, 0, false);
        int p1 = __builtin_amdgcn_cvt_pk_fp8_f32(v.z, v.w, 0, false);
        q[j4 * 4 + 0] = (unsigned char)(p0 & 0xFF);
        q[j4 * 4 + 1] = (unsigned char)((p0 >> 8) & 0xFF);
        q[j4 * 4 + 2] = (unsigned char)(p1 & 0xFF);
        q[j4 * 4 + 3] = (unsigned char)((p1 >> 8) & 0xFF);
    }
    const int N_ = r0 >> 7, rg = (r0 >> 4) & 7;
    char* base = (char*)Cq + ((size_t)((N_ * 4 + K_) * 8 + rg)) * 2048;
    *(uint4*)(base + lane * 16) = *(uint4*)&q[0];
    *(uint4*)(base + 1024 + lane * 16) = *(uint4*)&q[16];
    // norms: fold kq subgroups (lane bits 4,5), then the 4 K_ waves via LDS
    s += __shfl_xor(s, 16);
    s += __shfl_xor(s, 32);
    __shared__ float red[4][16];
    if (lane < 16) red[wave][l15] = s;
    __syncthreads();
    if (tid < 16) cnorm[r0 + tid] = red[0][tid] + red[1][tid] + red[2][tid] + red[3][tid];
}

// ---- kernel 3: MX-fp8 GEMM, A-strip resident in LDS, B from L2 into registers ----
__global__ __launch_bounds__(256, 2) void triplet_main(
    const unsigned char* __restrict__ Zq, const unsigned char* __restrict__ Cq,
    const float* __restrict__ cnorm, const int* __restrict__ teacher,
    unsigned int* __restrict__ minq) {
    __shared__ __align__(16) unsigned char As[65536];  // full 128-row x 512-k strip

    const int M_ = blockIdx.x;   // x-major => XCD = M_ % 8 for all nq: strip stays L2-local
    const int nq = blockIdx.y;   // 0..7
    const int m0 = M_ * 128;
    const int tid = threadIdx.x;
    const int wave = tid >> 6, lane = tid & 63;
    const int wr = wave >> 1, wc = wave & 1;
    const int l15 = lane & 15, quad = lane >> 4;

    // stage the whole A strip once (64 chunks of 1 KB; 16 per wave), single barrier
    {
        const char* gA = (const char*)Zq + (size_t)M_ * 65536 + wave * 16384 + lane * 16;
        char* lA = (char*)As + wave * 16384;
#pragma unroll
        for (int i = 0; i < 16; i++) async_copy16(gA + i * 1024, lA + i * 1024);
    }

    unsigned int minu[4][4];
    int tch[4][4];
#pragma unroll
    for (int mi = 0; mi < 4; mi++)
#pragma unroll
        for (int r = 0; r < 4; r++) {
            minu[mi][r] = 0xFFFFFFFFu;
            tch[mi][r] = teacher[m0 + wr * 64 + mi * 16 + quad * 4 + r];
        }
    __syncthreads();  // A resident; no barriers after this point

    for (int nt = 0; nt < 4; nt++) {
        const int N_ = nq * 4 + nt;
        const int n0 = N_ * 128;
        const char* tB = (const char*)Cq + (size_t)N_ * 4 * 16384 + (wc * 4) * 2048 + lane * 16;
        f32x4 acc[4][4] = {};
        uint4 bq[4][2];
#pragma unroll
        for (int ni = 0; ni < 4; ni++) {
            bq[ni][0] = *(const uint4*)(tB + ni * 2048);
            bq[ni][1] = *(const uint4*)(tB + ni * 2048 + 1024);
        }
#pragma unroll
        for (int kt = 0; kt < 4; kt++) {
            uint4 bn[4][2];
            if (kt < 3) {
                const char* nB = tB + (kt + 1) * 16384;
#pragma unroll
                for (int ni = 0; ni < 4; ni++) {  // prefetch next kt's B (L2-resident)
                    bn[ni][0] = *(const uint4*)(nB + ni * 2048);
                    bn[ni][1] = *(const uint4*)(nB + ni * 2048 + 1024);
                }
            }
            v8i av[4];
#pragma unroll
            for (int mi = 0; mi < 4; mi++) {
                union { uint4 q[2]; v8i v; } u;
                const unsigned char* fb = As + ((kt * 8) + (wr * 4 + mi)) * 2048 + lane * 16;
                u.q[0] = *(const uint4*)fb;
                u.q[1] = *(const uint4*)(fb + 1024);
                av[mi] = u.v;
            }
#pragma unroll
            for (int mi = 0; mi < 4; mi++)
#pragma unroll
                for (int ni = 0; ni < 4; ni++) {
                    union { uint4 q[2]; v8i v; } u;
                    u.q[0] = bq[ni][0]; u.q[1] = bq[ni][1];
                    acc[mi][ni] = __builtin_amdgcn_mfma_scale_f32_16x16x128_f8f6f4(
                        av[mi], u.v, acc[mi][ni], 0, 0,
                        0, 0x7F7F7F7F, 0, 0x7F7F7F7F);  // scales = 1.0 (e8m0 127)
                }
            if (kt < 3) {
#pragma unroll
                for (int ni = 0; ni < 4; ni++) { bq[ni][0] = bn[ni][0]; bq[ni][1] = bn[ni][1]; }
            }
        }

        // fold: packed umin of (val-bits | col), teacher excluded
        float cn[4]; int col[4];
#pragma unroll
        for (int ni = 0; ni < 4; ni++) {
            col[ni] = n0 + wc * 64 + ni * 16 + l15;
            cn[ni] = cnorm[col[ni]];
        }
#pragma unroll
        for (int mi = 0; mi < 4; mi++)
#pragma unroll
            for (int r = 0; r < 4; r++) {
                int t = tch[mi][r];
#pragma unroll
                for (int ni = 0; ni < 4; ni++) {
                    float val = fmaxf(fmaf(-2.0f, acc[mi][ni][r], cn[ni]), 0.0f);
                    unsigned int u = (__builtin_bit_cast(unsigned int, val) & 0xFFFFF000u)
                                     | (unsigned int)col[ni];
                    u = (col[ni] == t) ? 0xFFFFFFFFu : u;
                    minu[mi][r] = min(minu[mi][r], u);
                }
            }
    }

    const int slot = nq * 2 + wc;  // 0..15
#pragma unroll
    for (int mi = 0; mi < 4; mi++)
#pragma unroll
        for (int r = 0; r < 4; r++) {
            unsigned int u = minu[mi][r];
#pragma unroll
            for (int off = 1; off < 16; off <<= 1) u = min(u, (unsigned int)__shfl_xor((int)u, off));
            if (l15 == 0) {
                int m = m0 + wr * 64 + mi * 16 + quad * 4 + r;
                minq[(size_t)slot * NM + m] = u;
            }
        }
}

// ---- kernel 4: refine — exact pos/neg distances + masked triplet block sums ----
__global__ void refine(const unsigned short* __restrict__ Zrm, const float* __restrict__ cb,
                       const unsigned int* __restrict__ minq, const int* __restrict__ teacher,
                       const int* __restrict__ lengths, float* __restrict__ blocksums) {
    const int tid = threadIdx.x, wave = tid >> 6, lane = tid & 63;
    const int m = blockIdx.x * 4 + wave;
    // combine the 16 slot argmins
    unsigned int u = minq[(size_t)(lane & 15) * NM + m];
    u = min(u, (unsigned int)__shfl_xor((int)u, 1));
    u = min(u, (unsigned int)__shfl_xor((int)u, 2));
    u = min(u, (unsigned int)__shfl_xor((int)u, 4));
    u = min(u, (unsigned int)__shfl_xor((int)u, 8));
    const int ng = (int)(u & 0xFFFu);
    const int tch = teacher[m];
    // exact distances: bf16 z, fp32 codebook, fp32 accum
    bf16x8 z8 = *(const bf16x8*)(Zrm + (size_t)m * ND + lane * 8);
    const float* cn_ = cb + (size_t)ng * ND + lane * 8;
    const float* ct_ = cb + (size_t)tch * ND + lane * 8;
    float an = 0.0f, at = 0.0f;
#pragma unroll
    for (int i = 0; i < 2; i++) {
        float4 vn = *(const float4*)(cn_ + i * 4);
        float4 vt = *(const float4*)(ct_ + i * 4);
        float z0 = (float)z8[i * 4 + 0], z1 = (float)z8[i * 4 + 1];
        float z2 = (float)z8[i * 4 + 2], z3 = (float)z8[i * 4 + 3];
        float d;
        d = z0 - vn.x; an += d * d;  d = z0 - vt.x; at += d * d;
        d = z1 - vn.y; an += d * d;  d = z1 - vt.y; at += d * d;
        d = z2 - vn.z; an += d * d;  d = z2 - vt.z; at += d * d;
        d = z3 - vn.w; an += d * d;  d = z3 - vt.w; at += d * d;
    }
#pragma unroll
    for (int off = 1; off < 64; off <<= 1) {
        an += __shfl_xor(an, off);
        at += __shfl_xor(at, off);
    }
    __shared__ float red[4];
    if (lane == 0) {
        float negd = sqrtf(fmaxf(an, 1e-12f));
        float posd = sqrtf(fmaxf(at, 1e-12f));
        float tri = fmaxf(posd - negd + MARGIN_F, 0.0f);
        int t = m & (NT - 1);
        int b = m >> 11;
        int flen = lengths[b] / ENC_STRIDE;
        red[wave] = (t < flen) ? tri : 0.0f;
    }
    __syncthreads();
    if (tid == 0) blocksums[blockIdx.x] = red[0] + red[1] + red[2] + red[3];
}

// ---- kernel 5: finalize over 4096 block sums ----
__global__ void finalize(const float* __restrict__ blocksums, const int* __restrict__ lengths,
                         float* __restrict__ out) {
    int tid = threadIdx.x;  // 256
    float s = 0.0f;
#pragma unroll
    for (int i = 0; i < 16; i++) s += blocksums[tid + i * 256];
#pragma unroll
    for (int off = 1; off < 64; off <<= 1) s += __shfl_xor(s, off);
    __shared__ float red[4];
    int lane = tid & 63, w = tid >> 6;
    if (lane == 0) red[w] = s;
    __syncthreads();
    if (tid == 0) {
        float cnt = 0.0f;
        for (int b = 0; b < NB; b++) cnt += (float)(lengths[b] / ENC_STRIDE);
        out[0] = (red[0] + red[1] + red[2] + red[3]) / (cnt + 1e-8f);
    }
}

extern "C" void kernel_launch(void* const* d_in, const int* in_sizes, int n_in,
                              void* d_out, int out_size, void* d_ws, size_t ws_size,
                              hipStream_t stream) {
    const float* sf = (const float*)d_in[0];
    const int* teacher = (const int*)d_in[1];
    const float* cb = (const float*)d_in[2];
    const int* lengths = (const int*)d_in[3];

    char* ws = (char*)d_ws;
    unsigned char* Zq = (unsigned char*)(ws);                  //  8,388,608 B
    unsigned char* Cq = (unsigned char*)(ws + 8388608);        //  2,097,152 B
    unsigned short* Zrm = (unsigned short*)(ws + 10485760);    // 16,777,216 B
    float* cnorm = (float*)(ws + 27262976);                    //     16,384 B
    unsigned int* minq = (unsigned int*)(ws + 27279360);       //  1,048,576 B
    float* blocksums = (float*)(ws + 28327936);                //     16,384 B

    student_prep<<<dim3(NT / 64, ND / 128, NB), 256, 0, stream>>>(sf, Zq, Zrm);
    codebook_prep<<<NCODES / 16, 256, 0, stream>>>(cb, Cq, cnorm);
    triplet_main<<<dim3(128, 8), 256, 0, stream>>>(Zq, Cq, cnorm, teacher, minq);
    refine<<<NM / 4, 256, 0, stream>>>(Zrm, cb, minq, teacher, lengths, blocksums);
    finalize<<<1, 256, 0, stream>>>(blocksums, lengths, (float*)d_out);
}

// Round 8
// 147.119 us; speedup vs baseline: 1.9580x; 1.1821x over previous
//
#include <hip/hip_runtime.h>
#include <hip/hip_bf16.h>

typedef __bf16 bf16x8 __attribute__((ext_vector_type(8)));
typedef float f32x4 __attribute__((ext_vector_type(4)));
typedef int v8i __attribute__((ext_vector_type(8)));

#define NB 8
#define ND 512
#define NT 2048
#define NCODES 4096
#define NM (NB * NT)
#define MARGIN_F 0.2f
#define ENC_STRIDE 320

// MX fragment image (Zq, Cq), fp8 e4m3:
//   tile (R_, K_) = 128 rows x 128 k = 16 KB at ((R_*4 + K_) * 16384)
//   fragment rg (0..7) = 16 rows x 128 k = 2048 B at rg*2048 within tile
//   bytes [0,1024): lane l's 16 B at l*16 = row rg*16+(l&15), k = (l>>4)*32 + 0..15
//   bytes [1024,2048): same lanes, k = (l>>4)*32 + 16..31

static __device__ inline unsigned short f2bf(float v) {
    __hip_bfloat16 h = __float2bfloat16(v);
    return __builtin_bit_cast(unsigned short, h);
}

static __device__ inline void async_copy16(const void* g, void* l) {
    __builtin_amdgcn_global_load_lds(
        (const __attribute__((address_space(1))) unsigned int*)g,
        (__attribute__((address_space(3))) unsigned int*)l, 16, 0, 0);
}

// ---- kernel 1: fused prep. blocks [0,1024): student tiles; [1024,1280): codebook ----
__global__ void prep_fused(const float* __restrict__ sf, const float* __restrict__ cb,
                           unsigned char* __restrict__ Zq, unsigned short* __restrict__ Zrm,
                           unsigned char* __restrict__ Cq, float* __restrict__ cnorm) {
    __shared__ float tile[128][65];
    __shared__ float redc[4][16];
    const int tid = threadIdx.x;  // 256
    const int wave = tid >> 6, lane = tid & 63, l15 = lane & 15, kq = lane >> 4;

    if (blockIdx.x < 1024) {
        // ---------- student path: (B,D,T) fp32 -> fp8 frag image + bf16 row-major ----------
        const int bx = blockIdx.x;
        const int t0 = (bx & 31) * 64;
        const int d0 = ((bx >> 5) & 3) * 128;
        const int b = bx >> 7;
        const float* src = sf + (size_t)b * ND * NT;
#pragma unroll
        for (int it = 0; it < 8; it++) {
            int idx = it * 256 + tid;
            int d = idx >> 4, t4 = (idx & 15) * 4;
            float4 v = *(const float4*)(src + (size_t)(d0 + d) * NT + t0 + t4);  // coalesced
            tile[d][t4] = v.x; tile[d][t4 + 1] = v.y; tile[d][t4 + 2] = v.z; tile[d][t4 + 3] = v.w;
        }
        __syncthreads();
        const int m0 = b * NT + t0;
        // fp8 fragment emit: wave w -> fragment rg0+w; lane: row w*16+l15, k kq*32+j
        {
            const int trow = wave * 16 + l15;
            unsigned char q[32];
#pragma unroll
            for (int j = 0; j < 32; j += 2) {
                float a = tile[kq * 32 + j][trow];
                float c = tile[kq * 32 + j + 1][trow];
                int p = __builtin_amdgcn_cvt_pk_fp8_f32(a, c, 0, false);
                q[j] = (unsigned char)(p & 0xFF);
                q[j + 1] = (unsigned char)((p >> 8) & 0xFF);
            }
            const int M_ = m0 >> 7, rg = ((m0 >> 4) & 7) + wave, K_ = d0 >> 7;
            char* base = (char*)Zq + ((size_t)((M_ * 4 + K_) * 8 + rg)) * 2048;
            *(uint4*)(base + lane * 16) = *(uint4*)&q[0];
            *(uint4*)(base + 1024 + lane * 16) = *(uint4*)&q[16];
        }
        // bf16 row-major emit for the refine kernel
        {
            int t = tid >> 2;
#pragma unroll
            for (int it = 0; it < 8; it++) {
                int d = (tid & 3) * 4 + it * 16;
                ushort4 o;
                o.x = f2bf(tile[d][t]); o.y = f2bf(tile[d + 1][t]);
                o.z = f2bf(tile[d + 2][t]); o.w = f2bf(tile[d + 3][t]);
                *(ushort4*)(Zrm + (size_t)(m0 + t) * ND + d0 + d) = o;
            }
        }
    } else {
        // ---------- codebook path: fp32 -> fp8 frag image + row norms ----------
        const int r0 = (blockIdx.x - 1024) * 16;
        const int row = r0 + l15;
        const int K_ = wave;  // each wave handles one 128-k quarter
        const float* src = cb + (size_t)row * ND + K_ * 128 + kq * 32;
        unsigned char q[32];
        float s = 0.0f;
#pragma unroll
        for (int j4 = 0; j4 < 8; j4++) {
            float4 v = *(const float4*)(src + j4 * 4);
            s += v.x * v.x + v.y * v.y + v.z * v.z + v.w * v.w;
            int p0 = __builtin_amdgcn_cvt_pk_fp8_f32(v.x, v.y, 0, false);
            int p1 = __builtin_amdgcn_cvt_pk_fp8_f32(v.z, v.w, 0, false);
            q[j4 * 4 + 0] = (unsigned char)(p0 & 0xFF);
            q[j4 * 4 + 1] = (unsigned char)((p0 >> 8) & 0xFF);
            q[j4 * 4 + 2] = (unsigned char)(p1 & 0xFF);
            q[j4 * 4 + 3] = (unsigned char)((p1 >> 8) & 0xFF);
        }
        const int N_ = r0 >> 7, rg = (r0 >> 4) & 7;
        char* base = (char*)Cq + ((size_t)((N_ * 4 + K_) * 8 + rg)) * 2048;
        *(uint4*)(base + lane * 16) = *(uint4*)&q[0];
        *(uint4*)(base + 1024 + lane * 16) = *(uint4*)&q[16];
        s += __shfl_xor(s, 16);
        s += __shfl_xor(s, 32);
        if (lane < 16) redc[wave][l15] = s;
        __syncthreads();
        if (tid < 16) cnorm[r0 + tid] = redc[0][tid] + redc[1][tid] + redc[2][tid] + redc[3][tid];
    }
}

// ---- kernel 2: MX-fp8 GEMM (R5 verbatim — measured 52 µs) ----
__global__ __launch_bounds__(256, 2) void triplet_main(
    const unsigned char* __restrict__ Zq, const unsigned char* __restrict__ Cq,
    const float* __restrict__ cnorm, const int* __restrict__ teacher,
    unsigned int* __restrict__ minq) {
    __shared__ __align__(16) unsigned char As[16384];
    __shared__ __align__(16) unsigned char Bs[16384];

    const int M_ = blockIdx.x;   // x-major => XCD = M_ % 8: strip-local L2 reuse
    const int nq = blockIdx.y;   // 0..7
    const int m0 = M_ * 128;
    const int tid = threadIdx.x;
    const int wave = tid >> 6, lane = tid & 63;
    const int wr = wave >> 1, wc = wave & 1;
    const int l15 = lane & 15, quad = lane >> 4;

    unsigned int minu[4][4];
    int tch[4][4];
#pragma unroll
    for (int mi = 0; mi < 4; mi++)
#pragma unroll
        for (int r = 0; r < 4; r++) {
            minu[mi][r] = 0xFFFFFFFFu;
            tch[mi][r] = teacher[m0 + wr * 64 + mi * 16 + quad * 4 + r];
        }

    const char* gA0 = (const char*)Zq + (size_t)M_ * 4 * 16384 + wave * 4096 + lane * 16;
    char* lA = (char*)As + wave * 4096;
    char* lB = (char*)Bs + wave * 4096;

    for (int nt = 0; nt < 4; nt++) {
        const int N_ = nq * 4 + nt;
        const int n0 = N_ * 128;
        const char* gA = gA0;
        const char* gB = (const char*)Cq + (size_t)N_ * 4 * 16384 + wave * 4096 + lane * 16;
        f32x4 acc[4][4] = {};

        for (int kt = 0; kt < 4; kt++) {
#pragma unroll
            for (int i = 0; i < 4; i++) {
                async_copy16(gA + i * 1024, lA + i * 1024);
                async_copy16(gB + i * 1024, lB + i * 1024);
            }
            gA += 16384; gB += 16384;
            __syncthreads();

            v8i av[4], bv[4];
#pragma unroll
            for (int mi = 0; mi < 4; mi++) {
                int rg = wr * 4 + mi;
                union { uint4 q[2]; v8i v; } u;
                u.q[0] = *(const uint4*)(As + rg * 2048 + lane * 16);
                u.q[1] = *(const uint4*)(As + rg * 2048 + 1024 + lane * 16);
                av[mi] = u.v;
            }
#pragma unroll
            for (int ni = 0; ni < 4; ni++) {
                int rg = wc * 4 + ni;
                union { uint4 q[2]; v8i v; } u;
                u.q[0] = *(const uint4*)(Bs + rg * 2048 + lane * 16);
                u.q[1] = *(const uint4*)(Bs + rg * 2048 + 1024 + lane * 16);
                bv[ni] = u.v;
            }
#pragma unroll
            for (int mi = 0; mi < 4; mi++)
#pragma unroll
                for (int ni = 0; ni < 4; ni++)
                    acc[mi][ni] = __builtin_amdgcn_mfma_scale_f32_16x16x128_f8f6f4(
                        av[mi], bv[ni], acc[mi][ni], 0, 0,
                        0, 0x7F7F7F7F, 0, 0x7F7F7F7F);  // scales = 1.0 (e8m0 127)
            __syncthreads();
        }

        // fold: packed umin of (val-bits | col), teacher excluded
        float cn[4]; int col[4];
#pragma unroll
        for (int ni = 0; ni < 4; ni++) {
            col[ni] = n0 + wc * 64 + ni * 16 + l15;
            cn[ni] = cnorm[col[ni]];
        }
#pragma unroll
        for (int mi = 0; mi < 4; mi++)
#pragma unroll
            for (int r = 0; r < 4; r++) {
                int t = tch[mi][r];
#pragma unroll
                for (int ni = 0; ni < 4; ni++) {
                    float val = fmaxf(fmaf(-2.0f, acc[mi][ni][r], cn[ni]), 0.0f);
                    unsigned int u = (__builtin_bit_cast(unsigned int, val) & 0xFFFFF000u)
                                     | (unsigned int)col[ni];
                    u = (col[ni] == t) ? 0xFFFFFFFFu : u;
                    minu[mi][r] = min(minu[mi][r], u);
                }
            }
    }

    const int slot = nq * 2 + wc;  // 0..15
#pragma unroll
    for (int mi = 0; mi < 4; mi++)
#pragma unroll
        for (int r = 0; r < 4; r++) {
            unsigned int u = minu[mi][r];
#pragma unroll
            for (int off = 1; off < 16; off <<= 1) u = min(u, (unsigned int)__shfl_xor((int)u, off));
            if (l15 == 0) {
                int m = m0 + wr * 64 + mi * 16 + quad * 4 + r;
                minq[(size_t)slot * NM + m] = u;
            }
        }
}

// ---- kernel 3: refine — exact pos/neg distances + masked triplet block sums ----
__global__ void refine(const unsigned short* __restrict__ Zrm, const float* __restrict__ cb,
                       const unsigned int* __restrict__ minq, const int* __restrict__ teacher,
                       const int* __restrict__ lengths, float* __restrict__ blocksums) {
    const int tid = threadIdx.x, wave = tid >> 6, lane = tid & 63;
    const int m = blockIdx.x * 4 + wave;
    unsigned int u = minq[(size_t)(lane & 15) * NM + m];
    u = min(u, (unsigned int)__shfl_xor((int)u, 1));
    u = min(u, (unsigned int)__shfl_xor((int)u, 2));
    u = min(u, (unsigned int)__shfl_xor((int)u, 4));
    u = min(u, (unsigned int)__shfl_xor((int)u, 8));
    const int ng = (int)(u & 0xFFFu);
    const int tch = teacher[m];
    bf16x8 z8 = *(const bf16x8*)(Zrm + (size_t)m * ND + lane * 8);
    const float* cn_ = cb + (size_t)ng * ND + lane * 8;
    const float* ct_ = cb + (size_t)tch * ND + lane * 8;
    float an = 0.0f, at = 0.0f;
#pragma unroll
    for (int i = 0; i < 2; i++) {
        float4 vn = *(const float4*)(cn_ + i * 4);
        float4 vt = *(const float4*)(ct_ + i * 4);
        float z0 = (float)z8[i * 4 + 0], z1 = (float)z8[i * 4 + 1];
        float z2 = (float)z8[i * 4 + 2], z3 = (float)z8[i * 4 + 3];
        float d;
        d = z0 - vn.x; an += d * d;  d = z0 - vt.x; at += d * d;
        d = z1 - vn.y; an += d * d;  d = z1 - vt.y; at += d * d;
        d = z2 - vn.z; an += d * d;  d = z2 - vt.z; at += d * d;
        d = z3 - vn.w; an += d * d;  d = z3 - vt.w; at += d * d;
    }
#pragma unroll
    for (int off = 1; off < 64; off <<= 1) {
        an += __shfl_xor(an, off);
        at += __shfl_xor(at, off);
    }
    __shared__ float red[4];
    if (lane == 0) {
        float negd = sqrtf(fmaxf(an, 1e-12f));
        float posd = sqrtf(fmaxf(at, 1e-12f));
        float tri = fmaxf(posd - negd + MARGIN_F, 0.0f);
        int t = m & (NT - 1);
        int b = m >> 11;
        int flen = lengths[b] / ENC_STRIDE;
        red[wave] = (t < flen) ? tri : 0.0f;
    }
    __syncthreads();
    if (tid == 0) blocksums[blockIdx.x] = red[0] + red[1] + red[2] + red[3];
}

// ---- kernel 4: finalize over 4096 block sums ----
__global__ void finalize(const float* __restrict__ blocksums, const int* __restrict__ lengths,
                         float* __restrict__ out) {
    int tid = threadIdx.x;  // 256
    float s = 0.0f;
#pragma unroll
    for (int i = 0; i < 16; i++) s += blocksums[tid + i * 256];
#pragma unroll
    for (int off = 1; off < 64; off <<= 1) s += __shfl_xor(s, off);
    __shared__ float red[4];
    int lane = tid & 63, w = tid >> 6;
    if (lane == 0) red[w] = s;
    __syncthreads();
    if (tid == 0) {
        float cnt = 0.0f;
        for (int b = 0; b < NB; b++) cnt += (float)(lengths[b] / ENC_STRIDE);
        out[0] = (red[0] + red[1] + red[2] + red[3]) / (cnt + 1e-8f);
    }
}

extern "C" void kernel_launch(void* const* d_in, const int* in_sizes, int n_in,
                              void* d_out, int out_size, void* d_ws, size_t ws_size,
                              hipStream_t stream) {
    const float* sf = (const float*)d_in[0];
    const int* teacher = (const int*)d_in[1];
    const float* cb = (const float*)d_in[2];
    const int* lengths = (const int*)d_in[3];

    char* ws = (char*)d_ws;
    unsigned char* Zq = (unsigned char*)(ws);                  //  8,388,608 B
    unsigned char* Cq = (unsigned char*)(ws + 8388608);        //  2,097,152 B
    unsigned short* Zrm = (unsigned short*)(ws + 10485760);    // 16,777,216 B
    float* cnorm = (float*)(ws + 27262976);                    //     16,384 B
    unsigned int* minq = (unsigned int*)(ws + 27279360);       //  1,048,576 B
    float* blocksums = (float*)(ws + 28327936);                //     16,384 B

    prep_fused<<<1280, 256, 0, stream>>>(sf, cb, Zq, Zrm, Cq, cnorm);
    triplet_main<<<dim3(128, 8), 256, 0, stream>>>(Zq, Cq, cnorm, teacher, minq);
    refine<<<NM / 4, 256, 0, stream>>>(Zrm, cb, minq, teacher, lengths, blocksums);
    finalize<<<1, 256, 0, stream>>>(blocksums, lengths, (float*)d_out);
}